// Round 8
// baseline (365.730 us; speedup 1.0000x reference)
//
#include <hip/hip_runtime.h>
#include <float.h>
#include <math.h>

#define NV 50257
#define D 128
#define B 2048
#define C 10

#define NVPAD 50272                 // 3142 * 16
#define NTILES (NVPAD / 16)         // 3142 col-tiles of 16
#define NSTREAM 128                 // vocab streams
#define NG4 (NVPAD * D / 4)         // int (=4 fp8) count of packed W_gen
#define LOG2E 1.44269504088896f
#define SC1 0x7F7F7F7F              // e8m0 scale = 1.0 in every byte

typedef __attribute__((ext_vector_type(8))) short short8;
typedef __attribute__((ext_vector_type(8))) int int8v;
typedef __attribute__((ext_vector_type(4))) float float4v;
typedef __attribute__((ext_vector_type(2))) float float2v;

__device__ __forceinline__ float softplus_f(float x) {
    return fmaxf(x, 0.f) + log1pf(expf(-fabsf(x)));
}

__device__ __forceinline__ short f2bf(float f) {
    unsigned u = __float_as_uint(f);
    unsigned r = (u + 0x7FFFu + ((u >> 16) & 1u)) >> 16;   // RNE
    return (short)r;
}

// ---------------- Kernel P: small-weight bf16 + bg2 table + out zero + done reset ----------
__global__ __launch_bounds__(256) void k_pre(
    const float* __restrict__ waff, const float* __restrict__ wmu,
    const float* __restrict__ wsig, const float* __restrict__ b_gen,
    short* __restrict__ waff_o, short* __restrict__ wmu_o,
    short* __restrict__ wsig_o, float* __restrict__ bg2,
    int* __restrict__ done_cnt, float* __restrict__ out)
{
    const int j = blockIdx.x * 256 + threadIdx.x;
    if (j == 0) out[0] = 0.f;
    if (j < 16384) {
        const float4* src; short4* dst; int jj;
        if (j < 8192)       { src = (const float4*)waff; dst = (short4*)waff_o; jj = j; }
        else if (j < 12288) { src = (const float4*)wmu;  dst = (short4*)wmu_o;  jj = j - 8192; }
        else                { src = (const float4*)wsig; dst = (short4*)wsig_o; jj = j - 12288; }
        const float4 g = src[jj];
        short4 o;
        o.x = f2bf(g.x); o.y = f2bf(g.y); o.z = f2bf(g.z); o.w = f2bf(g.w);
        dst[jj] = o;
    } else {
        const int jj = j - 16384;
        if (jj < NVPAD / 4) {
            const int e0 = jj * 4;
            float4 o;
            o.x = (e0 + 0 < NV) ? b_gen[e0 + 0] * LOG2E : -INFINITY;
            o.y = (e0 + 1 < NV) ? b_gen[e0 + 1] * LOG2E : -INFINITY;
            o.z = (e0 + 2 < NV) ? b_gen[e0 + 2] * LOG2E : -INFINITY;
            o.w = (e0 + 3 < NV) ? b_gen[e0 + 3] * LOG2E : -INFINITY;
            ((float4*)bg2)[jj] = o;
        } else if (jj < NVPAD / 4 + 8) {
            done_cnt[jj - NVPAD / 4] = 0;        // workspace is poisoned every iteration
        }
    }
}

// ---------------- Kernel M: fused [inference net (blocks 0..127)] + [W_gen->fp8 conv] ------
// Exact r1 structure (session-best total 178.6us). launch_bounds(640,1) keeps the
// inference live set spill-free; conversion overlaps the latency-bound inference blocks.
#define CONVB 629                   // ceil(NG4 / (640*4))
__global__ __launch_bounds__(640, 1) void k_main(
    const int* __restrict__ x_batch, const int* __restrict__ ctxw,
    const float* __restrict__ eps, const float* __restrict__ inf_emb,
    const short* __restrict__ waff_bf, const float* __restrict__ b_aff,
    const short* __restrict__ wmu_bf, const float* __restrict__ b_mu,
    const short* __restrict__ wsig_bf, const float* __restrict__ b_sig,
    const float* __restrict__ gen_sig_emb, const float* __restrict__ wg,
    unsigned char* __restrict__ w8,
    float* __restrict__ z_out, unsigned char* __restrict__ z8_out,
    float* __restrict__ kl_out)
{
    const int bid = blockIdx.x;
    const int t = threadIdx.x;

    __shared__ float us[16][132];        // U tile, C-layout (8.4 KB)
    __shared__ float hsp[5][16][132];    // relu partials, 5 slabs (42.2 KB)
    __shared__ float kl_s[8][16];

    if (bid >= 128) {
        // ---- conversion path: 4 strided int-writes (16 fp8) per thread ----
        const int base = (bid - 128) * (640 * 4) + t;
        #pragma unroll
        for (int k = 0; k < 4; ++k) {
            const int i4 = base + k * 640;
            if (i4 < NG4) {
                const int e0 = i4 * 4;
                int pk = 0;
                if (e0 < NV * D) {
                    const float4 g = ((const float4*)wg)[i4];
                    pk = __builtin_amdgcn_cvt_pk_fp8_f32(g.x, g.y, 0, false);
                    pk = __builtin_amdgcn_cvt_pk_fp8_f32(g.z, g.w, pk, true);
                }
                ((int*)w8)[i4] = pk;
            }
        }
        return;
    }

    // ---- inference path ----
    const int b0 = bid * 16;
    const int wv = t >> 6;           // 0..9
    const int lane = t & 63;
    const int col16 = lane & 15;
    const int quad = lane >> 4;
    const int brow = b0 + col16;

    // context gather: exactly one ctx per wave
    const int widx = ctxw[brow * C + wv];
    short8 cx[4];
    #pragma unroll
    for (int ks = 0; ks < 4; ++ks) {
        const float* p = inf_emb + (size_t)widx * D + ks * 32 + quad * 8;
        const float4 g0 = *(const float4*)p;
        const float4 g1 = *(const float4*)(p + 4);
        short8 v;
        v[0] = f2bf(g0.x); v[1] = f2bf(g0.y); v[2] = f2bf(g0.z); v[3] = f2bf(g0.w);
        v[4] = f2bf(g1.x); v[5] = f2bf(g1.y); v[6] = f2bf(g1.z); v[7] = f2bf(g1.w);
        cx[ks] = v;
    }

    // U phase: wave wv (<8) computes dt-tile wv once, shares via LDS
    if (wv < 8) {
        const int cidx = x_batch[brow];
        short8 ce[4];
        #pragma unroll
        for (int ks = 0; ks < 4; ++ks) {
            const float* p = inf_emb + (size_t)cidx * D + ks * 32 + quad * 8;
            const float4 g0 = *(const float4*)p;
            const float4 g1 = *(const float4*)(p + 4);
            short8 v;
            v[0] = f2bf(g0.x); v[1] = f2bf(g0.y); v[2] = f2bf(g0.z); v[3] = f2bf(g0.w);
            v[4] = f2bf(g1.x); v[5] = f2bf(g1.y); v[6] = f2bf(g1.z); v[7] = f2bf(g1.w);
            ce[ks] = v;
        }
        float4v acc = {0.f, 0.f, 0.f, 0.f};
        #pragma unroll
        for (int ks = 0; ks < 4; ++ks) {
            const short8 bw = *(const short8*)(waff_bf + (wv * 16 + col16) * 256 + ks * 32 + quad * 8);
            acc = __builtin_amdgcn_mfma_f32_16x16x32_bf16(ce[ks], bw, acc, 0, 0, 0);
        }
        #pragma unroll
        for (int r = 0; r < 4; ++r)
            us[quad * 4 + r][wv * 16 + col16] = acc[r];
    }
    __syncthreads();

    // all 10 waves: own ctx GEMM + relu into registers
    float ba[8];
    #pragma unroll
    for (int dt = 0; dt < 8; ++dt) ba[dt] = b_aff[dt * 16 + col16];

    float4v H[8];
    #pragma unroll
    for (int dt = 0; dt < 8; ++dt) {
        float4v a = {0.f, 0.f, 0.f, 0.f};
        #pragma unroll
        for (int ks = 0; ks < 4; ++ks) {
            const short8 bw = *(const short8*)(waff_bf + (dt * 16 + col16) * 256 + 128 + ks * 32 + quad * 8);
            a = __builtin_amdgcn_mfma_f32_16x16x32_bf16(cx[ks], bw, a, 0, 0, 0);
        }
        #pragma unroll
        for (int r = 0; r < 4; ++r) {
            const float u = us[quad * 4 + r][dt * 16 + col16];
            H[dt][r] = fmaxf(u + a[r] + ba[dt], 0.f);
        }
    }

    // two-phase slab commit: waves 0-4 write, waves 5-9 accumulate
    if (wv < 5) {
        #pragma unroll
        for (int dt = 0; dt < 8; ++dt)
            #pragma unroll
            for (int r = 0; r < 4; ++r)
                hsp[wv][quad * 4 + r][dt * 16 + col16] = H[dt][r];
    }
    __syncthreads();
    if (wv >= 5) {
        #pragma unroll
        for (int dt = 0; dt < 8; ++dt)
            #pragma unroll
            for (int r = 0; r < 4; ++r)
                hsp[wv - 5][quad * 4 + r][dt * 16 + col16] += H[dt][r];
    }
    __syncthreads();

    // waves 0..7: sum 5 slabs -> A-frags, GEMM2 (nt=wv), epilogue
    if (wv < 8) {
        short8 ha[4];
        #pragma unroll
        for (int ks = 0; ks < 4; ++ks) {
            const int off = ks * 32 + quad * 8;
            float4 s0 = {0.f, 0.f, 0.f, 0.f}, s1 = {0.f, 0.f, 0.f, 0.f};
            #pragma unroll
            for (int w = 0; w < 5; ++w) {
                const float4 a0 = *(const float4*)&hsp[w][col16][off];
                const float4 a1 = *(const float4*)&hsp[w][col16][off + 4];
                s0.x += a0.x; s0.y += a0.y; s0.z += a0.z; s0.w += a0.w;
                s1.x += a1.x; s1.y += a1.y; s1.z += a1.z; s1.w += a1.w;
            }
            short8 v;
            v[0] = f2bf(s0.x); v[1] = f2bf(s0.y); v[2] = f2bf(s0.z); v[3] = f2bf(s0.w);
            v[4] = f2bf(s1.x); v[5] = f2bf(s1.y); v[6] = f2bf(s1.z); v[7] = f2bf(s1.w);
            ha[ks] = v;
        }

        int xb2[4];
        #pragma unroll
        for (int r = 0; r < 4; ++r) xb2[r] = x_batch[b0 + quad * 4 + r];

        const int nt = wv;
        float4v mu4 = {0.f, 0.f, 0.f, 0.f};
        float4v sg4 = {0.f, 0.f, 0.f, 0.f};
        #pragma unroll
        for (int ks = 0; ks < 4; ++ks) {
            const short8 bm = *(const short8*)(wmu_bf + (nt * 16 + col16) * 128 + ks * 32 + quad * 8);
            const short8 bs = *(const short8*)(wsig_bf + (nt * 16 + col16) * 128 + ks * 32 + quad * 8);
            mu4 = __builtin_amdgcn_mfma_f32_16x16x32_bf16(ha[ks], bm, mu4, 0, 0, 0);
            sg4 = __builtin_amdgcn_mfma_f32_16x16x32_bf16(ha[ks], bs, sg4, 0, 0, 0);
        }
        const int d = nt * 16 + col16;
        const float bmu = b_mu[d];
        const float bsg = b_sig[d];
        float klp[4];
        #pragma unroll
        for (int r = 0; r < 4; ++r) {
            const int b = b0 + quad * 4 + r;
            const float mu = mu4[r] + bmu;
            const float sg = sg4[r] + bsg;
            const float isig = softplus_f(sg);
            const float e = eps[b * D + d];
            const float zz = fmaf(e, isig, mu);
            z_out[b * D + d] = zz;
            const int pk = __builtin_amdgcn_cvt_pk_fp8_f32(zz * LOG2E, 0.f, 0, false);
            z8_out[b * D + d] = (unsigned char)(pk & 0xFF);
            const float gs = softplus_f(gen_sig_emb[(size_t)xb2[r] * D + d]);
            const float diff = mu - gs;
            klp[r] = logf(gs / isig) + (isig * isig + diff * diff) / (2.f * gs * gs) - 0.5f;
        }
        #pragma unroll
        for (int off = 1; off < 16; off <<= 1)
            #pragma unroll
            for (int r = 0; r < 4; ++r)
                klp[r] += __shfl_xor(klp[r], off, 64);
        if (col16 == 0) {
            #pragma unroll
            for (int r = 0; r < 4; ++r)
                kl_s[wv][quad * 4 + r] = klp[r];
        }
    }
    __syncthreads();
    if (t < 16) {
        float s = 0.f;
        #pragma unroll
        for (int w = 0; w < 8; ++w) s += kl_s[w][t];
        kl_out[b0 + t] = s;
    }
}

// ---------------- Kernel B+C merged: MX-fp8 LSE sum-exp, last-block finalize ----------
// Per row-group x (256 rows), 128 stream-blocks write part_s then atomically bump
// done_cnt[x]; the 128th arrival (device-scope fence + atomic, per G16) performs the
// old k_final's work for those 256 rows inline. Saves one dispatch + launch gap.
#define LOADT8(bf, g, T) { \
    const int v_ = (T) < NTILES; \
    const int tt_ = v_ ? (T) : 0; \
    bf = *(const int8v*)(w8 + (size_t)(tt_ * 16 + col16) * D + quad * 32); \
    g = v_ ? bg2t[tt_ * 16 + col16] : -INFINITY; }

#define COMP8(bf, g) { \
    _Pragma("unroll") \
    for (int rt = 0; rt < 4; ++rt) { \
        float4v c = {g, g, g, g}; \
        c = __builtin_amdgcn_mfma_scale_f32_16x16x128_f8f6f4( \
                afrag[rt], bf, c, 0, 0, 0, SC1, 0, SC1); \
        _Pragma("unroll") \
        for (int r = 0; r < 4; ++r) \
            sums[rt][r] += __builtin_amdgcn_exp2f(c[r]); \
    } }

__global__ __launch_bounds__(256) void k_lse_final(
    const unsigned char* __restrict__ z8, const unsigned char* __restrict__ w8,
    const float* __restrict__ bg2t, float* __restrict__ part_s,
    const float* __restrict__ z, const float* __restrict__ b_gen,
    const int* __restrict__ ctxw, const float* __restrict__ kl,
    int* __restrict__ done_cnt, float* __restrict__ out)
{
    const int bid = blockIdx.x;
    const int s = bid & 127;                        // stream; XCD = s%8
    const int x = bid >> 7;                         // row block (256 rows)
    const int t = threadIdx.x;
    const int wv = t >> 6;
    const int lane = t & 63;
    const int col16 = lane & 15;
    const int quad = lane >> 4;
    const int rowbase = x * 256 + wv * 64;

    __shared__ int is_last;
    __shared__ float red[4];

    int8v afrag[4];
    #pragma unroll
    for (int rt = 0; rt < 4; ++rt)
        afrag[rt] = *(const int8v*)(z8 + (size_t)(rowbase + rt * 16 + col16) * D + quad * 32);

    float sums[4][4];
    #pragma unroll
    for (int rt = 0; rt < 4; ++rt)
        #pragma unroll
        for (int r = 0; r < 4; ++r) sums[rt][r] = 0.f;

    // exactly 25 tiles (streams s>=70 have 24; only the last is clamped -> -inf).
    int8v bA, bB, bC, bD;
    float gA, gB, gC, gD;
    LOADT8(bA, gA, s);
    LOADT8(bB, gB, s + 128);
    LOADT8(bC, gC, s + 256);
    LOADT8(bD, gD, s + 384);
    #pragma unroll 1
    for (int j = 0; j < 20; j += 4) {               // computes tiles j..j+3
        COMP8(bA, gA); LOADT8(bA, gA, s + (j + 4) * 128);
        COMP8(bB, gB); LOADT8(bB, gB, s + (j + 5) * 128);
        COMP8(bC, gC); LOADT8(bC, gC, s + (j + 6) * 128);
        COMP8(bD, gD); LOADT8(bD, gD, s + (j + 7) * 128);
    }
    COMP8(bA, gA);                                  // tile 20
    COMP8(bB, gB); COMP8(bC, gC); COMP8(bD, gD);    // tiles 21..23
    LOADT8(bA, gA, s + 24 * 128);
    COMP8(bA, gA);                                  // tile 24 (clamped for s>=70)

    #pragma unroll
    for (int off = 1; off < 16; off <<= 1)
        #pragma unroll
        for (int rt = 0; rt < 4; ++rt)
            #pragma unroll
            for (int r = 0; r < 4; ++r)
                sums[rt][r] += __shfl_xor(sums[rt][r], off, 64);

    if (col16 == 0) {
        #pragma unroll
        for (int rt = 0; rt < 4; ++rt)
            #pragma unroll
            for (int r = 0; r < 4; ++r) {
                const int row = rowbase + rt * 16 + quad * 4 + r;
                part_s[row * NSTREAM + s] = sums[rt][r];
            }
    }

    // ---- last-block-per-row-group finalize ----
    __threadfence();                                // release part_s stores (device scope)
    if (t == 0) {
        const int old = atomicAdd(&done_cnt[x], 1);
        is_last = (old == 127);
    }
    __syncthreads();
    if (!is_last) return;
    __threadfence();                                // acquire other blocks' part_s

    float wsum = 0.f;
    #pragma unroll 2
    for (int rr = 0; rr < 64; ++rr) {
        const int b = x * 256 + wv * 64 + rr;

        int idxs[C];
        #pragma unroll
        for (int c = 0; c < C; ++c) idxs[c] = ctxw[b * C + c];
        unsigned short uw[C];
        #pragma unroll
        for (int c = 0; c < C; ++c)
            uw[c] = *(const unsigned short*)(w8 + (size_t)idxs[c] * D + lane * 2);
        float sum_bg = 0.f;
        #pragma unroll
        for (int c = 0; c < C; ++c) sum_bg += b_gen[idxs[c]];

        float sv = part_s[b * NSTREAM + lane] + part_s[b * NSTREAM + 64 + lane];
        const float z0 = z[b * D + lane * 2];
        const float z1 = z[b * D + lane * 2 + 1];

        float acc = 0.f;
        #pragma unroll
        for (int c = 0; c < C; ++c) {
            const float2v wf = __builtin_amdgcn_cvt_pk_f32_fp8((int)uw[c], false);
            acc = fmaf(z0, wf[0], acc);
            acc = fmaf(z1, wf[1], acc);
        }
        #pragma unroll
        for (int off = 32; off > 0; off >>= 1) {
            sv  += __shfl_xor(sv, off, 64);
            acc += __shfl_xor(acc, off, 64);
        }
        if (lane == 0) {
            const float lse = logf(sv);
            const float recon = acc + sum_bg - C * lse;
            wsum += kl[b] - recon;
        }
    }
    if (lane == 0) red[wv] = wsum;
    __syncthreads();
    if (t == 0) atomicAdd(out, (red[0] + red[1] + red[2] + red[3]) * (1.f / B));
}

extern "C" void kernel_launch(void* const* d_in, const int* in_sizes, int n_in,
                              void* d_out, int out_size, void* d_ws, size_t ws_size,
                              hipStream_t stream) {
    const int* x_batch = (const int*)d_in[0];
    const int* ctxw    = (const int*)d_in[1];
    const float* eps   = (const float*)d_in[2];
    const float* inf_emb = (const float*)d_in[3];
    const float* W_aff = (const float*)d_in[4];
    const float* b_aff = (const float*)d_in[5];
    const float* W_mu  = (const float*)d_in[6];
    const float* b_mu  = (const float*)d_in[7];
    const float* W_sig = (const float*)d_in[8];
    const float* b_sig = (const float*)d_in[9];
    const float* gen_sig = (const float*)d_in[10];
    const float* W_gen = (const float*)d_in[11];
    const float* b_gen = (const float*)d_in[12];
    float* out = (float*)d_out;

    char* ws = (char*)d_ws;
    float* z      = (float*)ws;   ws += (size_t)B * D * 4;
    float* part_s = (float*)ws;   ws += (size_t)B * NSTREAM * 4;
    float* kl     = (float*)ws;   ws += (size_t)B * 4;
    float* bg2    = (float*)ws;   ws += (size_t)NVPAD * 4;
    unsigned char* z8 = (unsigned char*)ws;  ws += (size_t)B * D;
    unsigned char* w8 = (unsigned char*)ws;  ws += (size_t)NVPAD * D;
    short* waff_bf = (short*)ws;  ws += (size_t)128 * 256 * 2;
    short* wmu_bf  = (short*)ws;  ws += (size_t)128 * 128 * 2;
    short* wsig_bf = (short*)ws;  ws += (size_t)128 * 128 * 2;
    int* done_cnt  = (int*)ws;    ws += 8 * sizeof(int);

    const int pre_items = 16384 + NVPAD / 4 + 8;
    hipLaunchKernelGGL(k_pre, dim3((pre_items + 255) / 256), dim3(256), 0, stream,
                       W_aff, W_mu, W_sig, b_gen,
                       waff_bf, wmu_bf, wsig_bf, bg2, done_cnt, out);
    hipLaunchKernelGGL(k_main, dim3(128 + CONVB), dim3(640), 0, stream,
                       x_batch, ctxw, eps, inf_emb, waff_bf, b_aff, wmu_bf, b_mu,
                       wsig_bf, b_sig, gen_sig, W_gen, w8, z, z8, kl);
    hipLaunchKernelGGL(k_lse_final, dim3(8 * NSTREAM), dim3(256), 0, stream,
                       z8, w8, bg2, part_s, z, b_gen, ctxw, kl, done_cnt, out);
}

// Round 9
// 207.735 us; speedup vs baseline: 1.7606x; 1.7606x over previous
//
#include <hip/hip_runtime.h>
#include <float.h>
#include <math.h>

#define NV 50257
#define D 128
#define B 2048
#define C 10

#define NVPAD 50272                 // 3142 * 16
#define NTILES (NVPAD / 16)         // 3142 col-tiles of 16
#define NSTREAM 128                 // vocab streams
#define NG4 (NVPAD * D / 4)         // int (=4 fp8) count of packed W_gen
#define LOG2E 1.44269504088896f
#define SC1 0x7F7F7F7F              // e8m0 scale = 1.0 in every byte

#define INFB 32                     // inference blocks (4 solo waves each, 16 rows/wave)
#define CONV256B 786                // ceil(NG4 / (256*8)) conversion blocks

typedef __attribute__((ext_vector_type(8))) short short8;
typedef __attribute__((ext_vector_type(8))) int int8v;
typedef __attribute__((ext_vector_type(4))) float float4v;
typedef __attribute__((ext_vector_type(2))) float float2v;

__device__ __forceinline__ float softplus_f(float x) {
    return fmaxf(x, 0.f) + log1pf(expf(-fabsf(x)));
}

__device__ __forceinline__ short f2bf(float f) {
    unsigned u = __float_as_uint(f);
    unsigned r = (u + 0x7FFFu + ((u >> 16) & 1u)) >> 16;   // RNE
    return (short)r;
}

// gather one embedding row set (16 rows x 512B) into 4 bf16x8 MFMA A-fragments
#define LOADEMB(dst, idx) { \
    const float* p_ = inf_emb + (size_t)(idx) * D; \
    _Pragma("unroll") \
    for (int ks_ = 0; ks_ < 4; ++ks_) { \
        const float4 g0_ = *(const float4*)(p_ + ks_ * 32 + quad * 8); \
        const float4 g1_ = *(const float4*)(p_ + ks_ * 32 + quad * 8 + 4); \
        short8 v_; \
        v_[0] = f2bf(g0_.x); v_[1] = f2bf(g0_.y); v_[2] = f2bf(g0_.z); v_[3] = f2bf(g0_.w); \
        v_[4] = f2bf(g1_.x); v_[5] = f2bf(g1_.y); v_[6] = f2bf(g1_.z); v_[7] = f2bf(g1_.w); \
        dst[ks_] = v_; } }

// per-ctx H accumulation: H[dt] += relu(U[dt] + ctx@Waff_ctx + b_aff)
#define ACCH(cxN) { \
    _Pragma("unroll") \
    for (int dt_ = 0; dt_ < 8; ++dt_) { \
        float4v a_ = {0.f, 0.f, 0.f, 0.f}; \
        _Pragma("unroll") \
        for (int ks_ = 0; ks_ < 4; ++ks_) { \
            const short8 bw_ = *(const short8*)(waff_bf + (dt_ * 16 + col16) * 256 + 128 + ks_ * 32 + quad * 8); \
            a_ = __builtin_amdgcn_mfma_f32_16x16x32_bf16(cxN[ks_], bw_, a_, 0, 0, 0); } \
        _Pragma("unroll") \
        for (int r_ = 0; r_ < 4; ++r_) \
            H[dt_][r_] += fmaxf(U[dt_][r_] + a_[r_] + ba[dt_], 0.f); } }

// ---------------- Kernel P: small-weight bf16 + bg2 table + out zero (r1, tiny) ------------
__global__ __launch_bounds__(256) void k_pre(
    const float* __restrict__ waff, const float* __restrict__ wmu,
    const float* __restrict__ wsig, const float* __restrict__ b_gen,
    short* __restrict__ waff_o, short* __restrict__ wmu_o,
    short* __restrict__ wsig_o, float* __restrict__ bg2, float* __restrict__ out)
{
    const int j = blockIdx.x * 256 + threadIdx.x;
    if (j == 0) out[0] = 0.f;
    if (j < 16384) {
        const float4* src; short4* dst; int jj;
        if (j < 8192)       { src = (const float4*)waff; dst = (short4*)waff_o; jj = j; }
        else if (j < 12288) { src = (const float4*)wmu;  dst = (short4*)wmu_o;  jj = j - 8192; }
        else                { src = (const float4*)wsig; dst = (short4*)wsig_o; jj = j - 12288; }
        const float4 g = src[jj];
        short4 o;
        o.x = f2bf(g.x); o.y = f2bf(g.y); o.z = f2bf(g.z); o.w = f2bf(g.w);
        dst[jj] = o;
    } else {
        const int jj = j - 16384;
        if (jj < NVPAD / 4) {
            const int e0 = jj * 4;
            float4 o;
            o.x = (e0 + 0 < NV) ? b_gen[e0 + 0] * LOG2E : -INFINITY;
            o.y = (e0 + 1 < NV) ? b_gen[e0 + 1] * LOG2E : -INFINITY;
            o.z = (e0 + 2 < NV) ? b_gen[e0 + 2] * LOG2E : -INFINITY;
            o.w = (e0 + 3 < NV) ? b_gen[e0 + 3] * LOG2E : -INFINITY;
            ((float4*)bg2)[jj] = o;
        }
    }
}

// ---------------- Kernel M: SOLO-WAVE inference (32 blocks) + W_gen->fp8 (786 blocks) ------
// ROUND 9: the invariant 42us was barrier-coupled gather-tail amplification: 10-wave
// blocks with ~10 barrier-separated phases, each paced by the slowest of ~160 random
// HBM gathers. Now each wave owns 16 batch rows END-TO-END (all 10 ctx, both GEMMs,
// epilogue): no cross-wave coupling, 40+ independent gathers in flight per wave
// (4-deep ctx pipeline, statically unrolled), one intra-block barrier only for the
// register->LDS->A-frag transpose (private per-wave LDS slab).
__global__ __launch_bounds__(256, 1) void k_main(
    const int* __restrict__ x_batch, const int* __restrict__ ctxw,
    const float* __restrict__ eps, const float* __restrict__ inf_emb,
    const short* __restrict__ waff_bf, const float* __restrict__ b_aff,
    const short* __restrict__ wmu_bf, const float* __restrict__ b_mu,
    const short* __restrict__ wsig_bf, const float* __restrict__ b_sig,
    const float* __restrict__ gen_sig_emb, const float* __restrict__ wg,
    unsigned char* __restrict__ w8,
    float* __restrict__ z_out, unsigned char* __restrict__ z8_out,
    float* __restrict__ kl_out)
{
    const int bid = blockIdx.x;
    const int t = threadIdx.x;

    __shared__ float h_lds[4][16][132];      // per-wave private slab (33.8 KB)

    if (bid >= INFB) {
        // ---- conversion path: 8 strided int-writes (32 fp8) per thread ----
        const int base = (bid - INFB) * (256 * 8) + t;
        #pragma unroll
        for (int k = 0; k < 8; ++k) {
            const int i4 = base + k * 256;
            if (i4 < NG4) {
                const int e0 = i4 * 4;
                int pk = 0;
                if (e0 < NV * D) {
                    const float4 g = ((const float4*)wg)[i4];
                    pk = __builtin_amdgcn_cvt_pk_fp8_f32(g.x, g.y, 0, false);
                    pk = __builtin_amdgcn_cvt_pk_fp8_f32(g.z, g.w, pk, true);
                }
                ((int*)w8)[i4] = pk;
            }
        }
        return;
    }

    // ---- inference: wave wv owns batch tile (bid*4 + wv), rows b0..b0+15 ----
    const int wv = t >> 6;
    const int lane = t & 63;
    const int col16 = lane & 15;
    const int quad = lane >> 4;
    const int b0 = (bid * 4 + wv) * 16;

    // all row indices up front (independent 4B gathers)
    int wi[10];
    #pragma unroll
    for (int c = 0; c < 10; ++c) wi[c] = ctxw[(b0 + col16) * C + c];
    const int cidx = x_batch[b0 + col16];

    // issue center + first 4 ctx row-gathers (40 independent VMEM ops in flight)
    short8 ce[4], cx0[4], cx1[4], cx2[4], cx3[4];
    LOADEMB(ce, cidx);
    LOADEMB(cx0, wi[0]);
    LOADEMB(cx1, wi[1]);
    LOADEMB(cx2, wi[2]);
    LOADEMB(cx3, wi[3]);

    float ba[8];
    #pragma unroll
    for (int dt = 0; dt < 8; ++dt) ba[dt] = b_aff[dt * 16 + col16];

    // U = center GEMM (all 8 dt tiles, this wave alone)
    float4v U[8];
    #pragma unroll
    for (int dt = 0; dt < 8; ++dt) {
        float4v acc = {0.f, 0.f, 0.f, 0.f};
        #pragma unroll
        for (int ks = 0; ks < 4; ++ks) {
            const short8 bw = *(const short8*)(waff_bf + (dt * 16 + col16) * 256 + ks * 32 + quad * 8);
            acc = __builtin_amdgcn_mfma_f32_16x16x32_bf16(ce[ks], bw, acc, 0, 0, 0);
        }
        U[dt] = acc;
    }

    float4v H[8];
    #pragma unroll
    for (int dt = 0; dt < 8; ++dt) H[dt] = (float4v){0.f, 0.f, 0.f, 0.f};

    // 4-deep rotating ctx pipeline (static slots -- no runtime indexing, rule #20)
    ACCH(cx0); LOADEMB(cx0, wi[4]);
    ACCH(cx1); LOADEMB(cx1, wi[5]);
    ACCH(cx2); LOADEMB(cx2, wi[6]);
    ACCH(cx3); LOADEMB(cx3, wi[7]);
    ACCH(cx0); LOADEMB(cx0, wi[8]);
    ACCH(cx1); LOADEMB(cx1, wi[9]);
    ACCH(cx2);
    ACCH(cx3);
    ACCH(cx0);
    ACCH(cx1);

    // transpose H (C/D layout) -> A-frag layout via private LDS slab
    #pragma unroll
    for (int dt = 0; dt < 8; ++dt)
        #pragma unroll
        for (int r = 0; r < 4; ++r)
            h_lds[wv][quad * 4 + r][dt * 16 + col16] = H[dt][r];
    __syncthreads();                 // single barrier (4 waves, own slabs; orders LDS)

    short8 ha[4];
    #pragma unroll
    for (int ks = 0; ks < 4; ++ks) {
        const int off = ks * 32 + quad * 8;
        const float4 a0 = *(const float4*)&h_lds[wv][col16][off];
        const float4 a1 = *(const float4*)&h_lds[wv][col16][off + 4];
        short8 v;
        v[0] = f2bf(a0.x); v[1] = f2bf(a0.y); v[2] = f2bf(a0.z); v[3] = f2bf(a0.w);
        v[4] = f2bf(a1.x); v[5] = f2bf(a1.y); v[6] = f2bf(a1.z); v[7] = f2bf(a1.w);
        ha[ks] = v;
    }

    int xb2[4];
    #pragma unroll
    for (int r = 0; r < 4; ++r) xb2[r] = x_batch[b0 + quad * 4 + r];

    float klp[4] = {0.f, 0.f, 0.f, 0.f};

    // GEMM2 + epilogue in two nt-halves (register pressure control)
    #pragma unroll
    for (int half = 0; half < 2; ++half) {
        // epilogue gathers for these 4 nt columns issued FIRST (latency overlap)
        float gsr[4][4], epr[4][4];
        #pragma unroll
        for (int n = 0; n < 4; ++n) {
            const int d = (half * 4 + n) * 16 + col16;
            #pragma unroll
            for (int r = 0; r < 4; ++r) {
                gsr[n][r] = gen_sig_emb[(size_t)xb2[r] * D + d];
                epr[n][r] = eps[(b0 + quad * 4 + r) * D + d];
            }
        }

        float4v mu[4], sg[4];
        #pragma unroll
        for (int n = 0; n < 4; ++n) {
            const int nt = half * 4 + n;
            float4v m_ = {0.f, 0.f, 0.f, 0.f};
            float4v s_ = {0.f, 0.f, 0.f, 0.f};
            #pragma unroll
            for (int ks = 0; ks < 4; ++ks) {
                const short8 bm = *(const short8*)(wmu_bf  + (nt * 16 + col16) * 128 + ks * 32 + quad * 8);
                const short8 bs = *(const short8*)(wsig_bf + (nt * 16 + col16) * 128 + ks * 32 + quad * 8);
                m_ = __builtin_amdgcn_mfma_f32_16x16x32_bf16(ha[ks], bm, m_, 0, 0, 0);
                s_ = __builtin_amdgcn_mfma_f32_16x16x32_bf16(ha[ks], bs, s_, 0, 0, 0);
            }
            mu[n] = m_; sg[n] = s_;
        }

        #pragma unroll
        for (int n = 0; n < 4; ++n) {
            const int d = (half * 4 + n) * 16 + col16;
            const float bmu = b_mu[d];
            const float bsg = b_sig[d];
            #pragma unroll
            for (int r = 0; r < 4; ++r) {
                const int b = b0 + quad * 4 + r;
                const float m = mu[n][r] + bmu;
                const float s = sg[n][r] + bsg;
                const float isig = softplus_f(s);
                const float zz = fmaf(epr[n][r], isig, m);
                z_out[b * D + d] = zz;
                const int pk = __builtin_amdgcn_cvt_pk_fp8_f32(zz * LOG2E, 0.f, 0, false);
                z8_out[b * D + d] = (unsigned char)(pk & 0xFF);
                const float gs = softplus_f(gsr[n][r]);
                const float diff = m - gs;
                klp[r] += logf(gs / isig) + (isig * isig + diff * diff) / (2.f * gs * gs) - 0.5f;
            }
        }
    }

    // in-wave KL reduce across the 16 d-columns (col16); no LDS, no barrier
    #pragma unroll
    for (int off = 1; off < 16; off <<= 1)
        #pragma unroll
        for (int r = 0; r < 4; ++r)
            klp[r] += __shfl_xor(klp[r], off, 64);
    if (col16 == 0) {
        #pragma unroll
        for (int r = 0; r < 4; ++r)
            kl_out[b0 + quad * 4 + r] = klp[r];
    }
}

// ---------------- Kernel B: MX-fp8 K=128 MFMA sum-exp, exact 25-tile pipeline (r1) --------
#define LOADT8(bf, g, T) { \
    const int v_ = (T) < NTILES; \
    const int tt_ = v_ ? (T) : 0; \
    bf = *(const int8v*)(w8 + (size_t)(tt_ * 16 + col16) * D + quad * 32); \
    g = v_ ? bg2t[tt_ * 16 + col16] : -INFINITY; }

#define COMP8(bf, g) { \
    _Pragma("unroll") \
    for (int rt = 0; rt < 4; ++rt) { \
        float4v c = {g, g, g, g}; \
        c = __builtin_amdgcn_mfma_scale_f32_16x16x128_f8f6f4( \
                afrag[rt], bf, c, 0, 0, 0, SC1, 0, SC1); \
        _Pragma("unroll") \
        for (int r = 0; r < 4; ++r) \
            sums[rt][r] += __builtin_amdgcn_exp2f(c[r]); \
    } }

__global__ __launch_bounds__(256) void k_lse_mfma(
    const unsigned char* __restrict__ z8, const unsigned char* __restrict__ w8,
    const float* __restrict__ bg2t, float* __restrict__ part_s)
{
    const int bid = blockIdx.x;
    const int s = bid & 127;                        // stream; XCD = s%8
    const int x = bid >> 7;                         // row block (256 rows)
    const int t = threadIdx.x;
    const int wv = t >> 6;
    const int lane = t & 63;
    const int col16 = lane & 15;
    const int quad = lane >> 4;
    const int rowbase = x * 256 + wv * 64;

    int8v afrag[4];
    #pragma unroll
    for (int rt = 0; rt < 4; ++rt)
        afrag[rt] = *(const int8v*)(z8 + (size_t)(rowbase + rt * 16 + col16) * D + quad * 32);

    float sums[4][4];
    #pragma unroll
    for (int rt = 0; rt < 4; ++rt)
        #pragma unroll
        for (int r = 0; r < 4; ++r) sums[rt][r] = 0.f;

    // exactly 25 tiles (streams s>=70 have 24; only the last is clamped -> -inf).
    int8v bA, bB, bC, bD;
    float gA, gB, gC, gD;
    LOADT8(bA, gA, s);
    LOADT8(bB, gB, s + 128);
    LOADT8(bC, gC, s + 256);
    LOADT8(bD, gD, s + 384);
    #pragma unroll 1
    for (int j = 0; j < 20; j += 4) {               // computes tiles j..j+3
        COMP8(bA, gA); LOADT8(bA, gA, s + (j + 4) * 128);
        COMP8(bB, gB); LOADT8(bB, gB, s + (j + 5) * 128);
        COMP8(bC, gC); LOADT8(bC, gC, s + (j + 6) * 128);
        COMP8(bD, gD); LOADT8(bD, gD, s + (j + 7) * 128);
    }
    COMP8(bA, gA);                                  // tile 20
    COMP8(bB, gB); COMP8(bC, gC); COMP8(bD, gD);    // tiles 21..23
    LOADT8(bA, gA, s + 24 * 128);
    COMP8(bA, gA);                                  // tile 24 (clamped for s>=70)

    #pragma unroll
    for (int off = 1; off < 16; off <<= 1)
        #pragma unroll
        for (int rt = 0; rt < 4; ++rt)
            #pragma unroll
            for (int r = 0; r < 4; ++r)
                sums[rt][r] += __shfl_xor(sums[rt][r], off, 64);

    if (col16 == 0) {
        #pragma unroll
        for (int rt = 0; rt < 4; ++rt)
            #pragma unroll
            for (int r = 0; r < 4; ++r) {
                const int row = rowbase + rt * 16 + quad * 4 + r;
                part_s[row * NSTREAM + s] = sums[rt][r];
            }
    }
}

// ---------------- Kernel C: finalize (fp8 ctx gather, L2-hot), one atomic/block (r1) --------
__global__ __launch_bounds__(256) void k_final(
    const float* __restrict__ z, const unsigned char* __restrict__ w8,
    const float* __restrict__ b_gen, const int* __restrict__ ctxw,
    const float* __restrict__ part_s, const float* __restrict__ kl,
    float* __restrict__ out)
{
    const int t = threadIdx.x;
    const int wv = t >> 6;
    const int lane = t & 63;
    __shared__ float red[4];

    float wsum = 0.f;
    #pragma unroll
    for (int rr = 0; rr < 2; ++rr) {
        const int b = blockIdx.x * 8 + wv * 2 + rr;

        int idxs[C];
        #pragma unroll
        for (int c = 0; c < C; ++c) idxs[c] = ctxw[b * C + c];
        unsigned short uw[C];
        #pragma unroll
        for (int c = 0; c < C; ++c)
            uw[c] = *(const unsigned short*)(w8 + (size_t)idxs[c] * D + lane * 2);
        float sum_bg = 0.f;
        #pragma unroll
        for (int c = 0; c < C; ++c) sum_bg += b_gen[idxs[c]];

        float sv = part_s[b * NSTREAM + lane] + part_s[b * NSTREAM + 64 + lane];
        const float z0 = z[b * D + lane * 2];
        const float z1 = z[b * D + lane * 2 + 1];

        float acc = 0.f;
        #pragma unroll
        for (int c = 0; c < C; ++c) {
            const float2v wf = __builtin_amdgcn_cvt_pk_f32_fp8((int)uw[c], false);
            acc = fmaf(z0, wf[0], acc);
            acc = fmaf(z1, wf[1], acc);
        }
        #pragma unroll
        for (int off = 32; off > 0; off >>= 1) {
            sv  += __shfl_xor(sv, off, 64);
            acc += __shfl_xor(acc, off, 64);
        }
        if (lane == 0) {
            const float lse = logf(sv);
            const float recon = acc + sum_bg - C * lse;
            wsum += kl[b] - recon;
        }
    }
    if (lane == 0) red[wv] = wsum;
    __syncthreads();
    if (t == 0) atomicAdd(out, (red[0] + red[1] + red[2] + red[3]) * (1.f / B));
}

extern "C" void kernel_launch(void* const* d_in, const int* in_sizes, int n_in,
                              void* d_out, int out_size, void* d_ws, size_t ws_size,
                              hipStream_t stream) {
    const int* x_batch = (const int*)d_in[0];
    const int* ctxw    = (const int*)d_in[1];
    const float* eps   = (const float*)d_in[2];
    const float* inf_emb = (const float*)d_in[3];
    const float* W_aff = (const float*)d_in[4];
    const float* b_aff = (const float*)d_in[5];
    const float* W_mu  = (const float*)d_in[6];
    const float* b_mu  = (const float*)d_in[7];
    const float* W_sig = (const float*)d_in[8];
    const float* b_sig = (const float*)d_in[9];
    const float* gen_sig = (const float*)d_in[10];
    const float* W_gen = (const float*)d_in[11];
    const float* b_gen = (const float*)d_in[12];
    float* out = (float*)d_out;

    char* ws = (char*)d_ws;
    float* z      = (float*)ws;   ws += (size_t)B * D * 4;
    float* part_s = (float*)ws;   ws += (size_t)B * NSTREAM * 4;
    float* kl     = (float*)ws;   ws += (size_t)B * 4;
    float* bg2    = (float*)ws;   ws += (size_t)NVPAD * 4;
    unsigned char* z8 = (unsigned char*)ws;  ws += (size_t)B * D;
    unsigned char* w8 = (unsigned char*)ws;  ws += (size_t)NVPAD * D;
    short* waff_bf = (short*)ws;  ws += (size_t)128 * 256 * 2;
    short* wmu_bf  = (short*)ws;  ws += (size_t)128 * 128 * 2;
    short* wsig_bf = (short*)ws;  ws += (size_t)128 * 128 * 2;

    const int pre_items = 16384 + NVPAD / 4;
    hipLaunchKernelGGL(k_pre, dim3((pre_items + 255) / 256), dim3(256), 0, stream,
                       W_aff, W_mu, W_sig, b_gen,
                       waff_bf, wmu_bf, wsig_bf, bg2, out);
    hipLaunchKernelGGL(k_main, dim3(INFB + CONV256B), dim3(256), 0, stream,
                       x_batch, ctxw, eps, inf_emb, waff_bf, b_aff, wmu_bf, b_mu,
                       wsig_bf, b_sig, gen_sig, W_gen, w8, z, z8, kl);
    hipLaunchKernelGGL(k_lse_mfma, dim3(8 * NSTREAM), dim3(256), 0, stream,
                       z8, w8, bg2, part_s);
    hipLaunchKernelGGL(k_final, dim3(B / 8), dim3(256), 0, stream,
                       z, w8, b_gen, ctxw, part_s, kl, out);
}

// Round 10
// 176.428 us; speedup vs baseline: 2.0730x; 1.1774x over previous
//
#include <hip/hip_runtime.h>
#include <float.h>
#include <math.h>

#define NV 50257
#define D 128
#define B 2048
#define C 10

#define NVPAD 50272                 // 3142 * 16
#define NTILES (NVPAD / 16)         // 3142 col-tiles of 16
#define NSTREAM 128                 // vocab streams
#define NG4 (NVPAD * D / 4)         // int (=4 fp8) count of packed W_gen
#define LOG2E 1.44269504088896f
#define SC1 0x7F7F7F7F              // e8m0 scale = 1.0 in every byte

typedef __attribute__((ext_vector_type(8))) short short8;
typedef __attribute__((ext_vector_type(8))) int int8v;
typedef __attribute__((ext_vector_type(4))) float float4v;
typedef __attribute__((ext_vector_type(2))) float float2v;

__device__ __forceinline__ float softplus_f(float x) {
    return fmaxf(x, 0.f) + log1pf(expf(-fabsf(x)));
}

__device__ __forceinline__ short f2bf(float f) {
    unsigned u = __float_as_uint(f);
    unsigned r = (u + 0x7FFFu + ((u >> 16) & 1u)) >> 16;   // RNE
    return (short)r;
}

// ---------------- Kernel P: small-weight bf16 + bg2 table + out zero (tiny) ----------------
__global__ __launch_bounds__(256) void k_pre(
    const float* __restrict__ waff, const float* __restrict__ wmu,
    const float* __restrict__ wsig, const float* __restrict__ b_gen,
    short* __restrict__ waff_o, short* __restrict__ wmu_o,
    short* __restrict__ wsig_o, float* __restrict__ bg2, float* __restrict__ out)
{
    const int j = blockIdx.x * 256 + threadIdx.x;
    if (j == 0) out[0] = 0.f;
    if (j < 16384) {
        const float4* src; short4* dst; int jj;
        if (j < 8192)       { src = (const float4*)waff; dst = (short4*)waff_o; jj = j; }
        else if (j < 12288) { src = (const float4*)wmu;  dst = (short4*)wmu_o;  jj = j - 8192; }
        else                { src = (const float4*)wsig; dst = (short4*)wsig_o; jj = j - 12288; }
        const float4 g = src[jj];
        short4 o;
        o.x = f2bf(g.x); o.y = f2bf(g.y); o.z = f2bf(g.z); o.w = f2bf(g.w);
        dst[jj] = o;
    } else {
        const int jj = j - 16384;
        if (jj < NVPAD / 4) {
            const int e0 = jj * 4;
            float4 o;
            o.x = (e0 + 0 < NV) ? b_gen[e0 + 0] * LOG2E : -INFINITY;
            o.y = (e0 + 1 < NV) ? b_gen[e0 + 1] * LOG2E : -INFINITY;
            o.z = (e0 + 2 < NV) ? b_gen[e0 + 2] * LOG2E : -INFINITY;
            o.w = (e0 + 3 < NV) ? b_gen[e0 + 3] * LOG2E : -INFINITY;
            ((float4*)bg2)[jj] = o;
        }
    }
}

// ---------------- Kernel M: fused [inference net (blocks 0..127)] + [W_gen->fp8 conv] ------
// Session-best structure (r1, measured 178.6us total). 640 thr = 10 waves, one ctx per
// wave; launch_bounds(640,1) keeps the inference live set spill-free; the conversion
// stream overlaps the latency-bound inference blocks (measured 3.5us better than
// serializing it into k_pre). k_main is parallelism-saturated: spreading blocks (r4),
// L3-warming (r6), coalesced staging (r7), barrier removal (r9) were all null/worse.
#define CONVB 629                   // ceil(NG4 / (640*4))
__global__ __launch_bounds__(640, 1) void k_main(
    const int* __restrict__ x_batch, const int* __restrict__ ctxw,
    const float* __restrict__ eps, const float* __restrict__ inf_emb,
    const short* __restrict__ waff_bf, const float* __restrict__ b_aff,
    const short* __restrict__ wmu_bf, const float* __restrict__ b_mu,
    const short* __restrict__ wsig_bf, const float* __restrict__ b_sig,
    const float* __restrict__ gen_sig_emb, const float* __restrict__ wg,
    unsigned char* __restrict__ w8,
    float* __restrict__ z_out, unsigned char* __restrict__ z8_out,
    float* __restrict__ kl_out)
{
    const int bid = blockIdx.x;
    const int t = threadIdx.x;

    __shared__ float us[16][132];        // U tile, C-layout (8.4 KB)
    __shared__ float hsp[5][16][132];    // relu partials, 5 slabs (42.2 KB)
    __shared__ float kl_s[8][16];

    if (bid >= 128) {
        // ---- conversion path: 4 strided int-writes (16 fp8) per thread ----
        const int base = (bid - 128) * (640 * 4) + t;
        #pragma unroll
        for (int k = 0; k < 4; ++k) {
            const int i4 = base + k * 640;
            if (i4 < NG4) {
                const int e0 = i4 * 4;
                int pk = 0;
                if (e0 < NV * D) {
                    const float4 g = ((const float4*)wg)[i4];
                    pk = __builtin_amdgcn_cvt_pk_fp8_f32(g.x, g.y, 0, false);
                    pk = __builtin_amdgcn_cvt_pk_fp8_f32(g.z, g.w, pk, true);
                }
                ((int*)w8)[i4] = pk;
            }
        }
        return;
    }

    // ---- inference path ----
    const int b0 = bid * 16;
    const int wv = t >> 6;           // 0..9
    const int lane = t & 63;
    const int col16 = lane & 15;
    const int quad = lane >> 4;
    const int brow = b0 + col16;

    // context gather: exactly one ctx per wave
    const int widx = ctxw[brow * C + wv];
    short8 cx[4];
    #pragma unroll
    for (int ks = 0; ks < 4; ++ks) {
        const float* p = inf_emb + (size_t)widx * D + ks * 32 + quad * 8;
        const float4 g0 = *(const float4*)p;
        const float4 g1 = *(const float4*)(p + 4);
        short8 v;
        v[0] = f2bf(g0.x); v[1] = f2bf(g0.y); v[2] = f2bf(g0.z); v[3] = f2bf(g0.w);
        v[4] = f2bf(g1.x); v[5] = f2bf(g1.y); v[6] = f2bf(g1.z); v[7] = f2bf(g1.w);
        cx[ks] = v;
    }

    // U phase: wave wv (<8) computes dt-tile wv once, shares via LDS
    if (wv < 8) {
        const int cidx = x_batch[brow];
        short8 ce[4];
        #pragma unroll
        for (int ks = 0; ks < 4; ++ks) {
            const float* p = inf_emb + (size_t)cidx * D + ks * 32 + quad * 8;
            const float4 g0 = *(const float4*)p;
            const float4 g1 = *(const float4*)(p + 4);
            short8 v;
            v[0] = f2bf(g0.x); v[1] = f2bf(g0.y); v[2] = f2bf(g0.z); v[3] = f2bf(g0.w);
            v[4] = f2bf(g1.x); v[5] = f2bf(g1.y); v[6] = f2bf(g1.z); v[7] = f2bf(g1.w);
            ce[ks] = v;
        }
        float4v acc = {0.f, 0.f, 0.f, 0.f};
        #pragma unroll
        for (int ks = 0; ks < 4; ++ks) {
            const short8 bw = *(const short8*)(waff_bf + (wv * 16 + col16) * 256 + ks * 32 + quad * 8);
            acc = __builtin_amdgcn_mfma_f32_16x16x32_bf16(ce[ks], bw, acc, 0, 0, 0);
        }
        #pragma unroll
        for (int r = 0; r < 4; ++r)
            us[quad * 4 + r][wv * 16 + col16] = acc[r];
    }
    __syncthreads();

    // all 10 waves: own ctx GEMM + relu into registers
    float ba[8];
    #pragma unroll
    for (int dt = 0; dt < 8; ++dt) ba[dt] = b_aff[dt * 16 + col16];

    float4v H[8];
    #pragma unroll
    for (int dt = 0; dt < 8; ++dt) {
        float4v a = {0.f, 0.f, 0.f, 0.f};
        #pragma unroll
        for (int ks = 0; ks < 4; ++ks) {
            const short8 bw = *(const short8*)(waff_bf + (dt * 16 + col16) * 256 + 128 + ks * 32 + quad * 8);
            a = __builtin_amdgcn_mfma_f32_16x16x32_bf16(cx[ks], bw, a, 0, 0, 0);
        }
        #pragma unroll
        for (int r = 0; r < 4; ++r) {
            const float u = us[quad * 4 + r][dt * 16 + col16];
            H[dt][r] = fmaxf(u + a[r] + ba[dt], 0.f);
        }
    }

    // two-phase slab commit: waves 0-4 write, waves 5-9 accumulate
    if (wv < 5) {
        #pragma unroll
        for (int dt = 0; dt < 8; ++dt)
            #pragma unroll
            for (int r = 0; r < 4; ++r)
                hsp[wv][quad * 4 + r][dt * 16 + col16] = H[dt][r];
    }
    __syncthreads();
    if (wv >= 5) {
        #pragma unroll
        for (int dt = 0; dt < 8; ++dt)
            #pragma unroll
            for (int r = 0; r < 4; ++r)
                hsp[wv - 5][quad * 4 + r][dt * 16 + col16] += H[dt][r];
    }
    __syncthreads();

    // waves 0..7: sum 5 slabs -> A-frags, GEMM2 (nt=wv), epilogue
    if (wv < 8) {
        short8 ha[4];
        #pragma unroll
        for (int ks = 0; ks < 4; ++ks) {
            const int off = ks * 32 + quad * 8;
            float4 s0 = {0.f, 0.f, 0.f, 0.f}, s1 = {0.f, 0.f, 0.f, 0.f};
            #pragma unroll
            for (int w = 0; w < 5; ++w) {
                const float4 a0 = *(const float4*)&hsp[w][col16][off];
                const float4 a1 = *(const float4*)&hsp[w][col16][off + 4];
                s0.x += a0.x; s0.y += a0.y; s0.z += a0.z; s0.w += a0.w;
                s1.x += a1.x; s1.y += a1.y; s1.z += a1.z; s1.w += a1.w;
            }
            short8 v;
            v[0] = f2bf(s0.x); v[1] = f2bf(s0.y); v[2] = f2bf(s0.z); v[3] = f2bf(s0.w);
            v[4] = f2bf(s1.x); v[5] = f2bf(s1.y); v[6] = f2bf(s1.z); v[7] = f2bf(s1.w);
            ha[ks] = v;
        }

        int xb2[4];
        #pragma unroll
        for (int r = 0; r < 4; ++r) xb2[r] = x_batch[b0 + quad * 4 + r];

        const int nt = wv;
        float4v mu4 = {0.f, 0.f, 0.f, 0.f};
        float4v sg4 = {0.f, 0.f, 0.f, 0.f};
        #pragma unroll
        for (int ks = 0; ks < 4; ++ks) {
            const short8 bm = *(const short8*)(wmu_bf + (nt * 16 + col16) * 128 + ks * 32 + quad * 8);
            const short8 bs = *(const short8*)(wsig_bf + (nt * 16 + col16) * 128 + ks * 32 + quad * 8);
            mu4 = __builtin_amdgcn_mfma_f32_16x16x32_bf16(ha[ks], bm, mu4, 0, 0, 0);
            sg4 = __builtin_amdgcn_mfma_f32_16x16x32_bf16(ha[ks], bs, sg4, 0, 0, 0);
        }
        const int d = nt * 16 + col16;
        const float bmu = b_mu[d];
        const float bsg = b_sig[d];
        float klp[4];
        #pragma unroll
        for (int r = 0; r < 4; ++r) {
            const int b = b0 + quad * 4 + r;
            const float mu = mu4[r] + bmu;
            const float sg = sg4[r] + bsg;
            const float isig = softplus_f(sg);
            const float e = eps[b * D + d];
            const float zz = fmaf(e, isig, mu);
            z_out[b * D + d] = zz;
            const int pk = __builtin_amdgcn_cvt_pk_fp8_f32(zz * LOG2E, 0.f, 0, false);
            z8_out[b * D + d] = (unsigned char)(pk & 0xFF);
            const float gs = softplus_f(gen_sig_emb[(size_t)xb2[r] * D + d]);
            const float diff = mu - gs;
            klp[r] = logf(gs / isig) + (isig * isig + diff * diff) / (2.f * gs * gs) - 0.5f;
        }
        #pragma unroll
        for (int off = 1; off < 16; off <<= 1)
            #pragma unroll
            for (int r = 0; r < 4; ++r)
                klp[r] += __shfl_xor(klp[r], off, 64);
        if (col16 == 0) {
            #pragma unroll
            for (int r = 0; r < 4; ++r)
                kl_s[wv][quad * 4 + r] = klp[r];
        }
    }
    __syncthreads();
    if (t < 16) {
        float s = 0.f;
        #pragma unroll
        for (int w = 0; w < 8; ++w) s += kl_s[w][t];
        kl_out[b0 + t] = s;
    }
}

// ---------------- Kernel B: MX-fp8 K=128 MFMA sum-exp, exact 25-tile pipeline ----------
#define LOADT8(bf, g, T) { \
    const int v_ = (T) < NTILES; \
    const int tt_ = v_ ? (T) : 0; \
    bf = *(const int8v*)(w8 + (size_t)(tt_ * 16 + col16) * D + quad * 32); \
    g = v_ ? bg2t[tt_ * 16 + col16] : -INFINITY; }

#define COMP8(bf, g) { \
    _Pragma("unroll") \
    for (int rt = 0; rt < 4; ++rt) { \
        float4v c = {g, g, g, g}; \
        c = __builtin_amdgcn_mfma_scale_f32_16x16x128_f8f6f4( \
                afrag[rt], bf, c, 0, 0, 0, SC1, 0, SC1); \
        _Pragma("unroll") \
        for (int r = 0; r < 4; ++r) \
            sums[rt][r] += __builtin_amdgcn_exp2f(c[r]); \
    } }

__global__ __launch_bounds__(256) void k_lse_mfma(
    const unsigned char* __restrict__ z8, const unsigned char* __restrict__ w8,
    const float* __restrict__ bg2t, float* __restrict__ part_s)
{
    const int bid = blockIdx.x;
    const int s = bid & 127;                        // stream; XCD = s%8
    const int x = bid >> 7;                         // row block (256 rows)
    const int t = threadIdx.x;
    const int wv = t >> 6;
    const int lane = t & 63;
    const int col16 = lane & 15;
    const int quad = lane >> 4;
    const int rowbase = x * 256 + wv * 64;

    int8v afrag[4];
    #pragma unroll
    for (int rt = 0; rt < 4; ++rt)
        afrag[rt] = *(const int8v*)(z8 + (size_t)(rowbase + rt * 16 + col16) * D + quad * 32);

    float sums[4][4];
    #pragma unroll
    for (int rt = 0; rt < 4; ++rt)
        #pragma unroll
        for (int r = 0; r < 4; ++r) sums[rt][r] = 0.f;

    // exactly 25 tiles (streams s>=70 have 24; only the last is clamped -> -inf).
    int8v bA, bB, bC, bD;
    float gA, gB, gC, gD;
    LOADT8(bA, gA, s);
    LOADT8(bB, gB, s + 128);
    LOADT8(bC, gC, s + 256);
    LOADT8(bD, gD, s + 384);
    #pragma unroll 1
    for (int j = 0; j < 20; j += 4) {               // computes tiles j..j+3
        COMP8(bA, gA); LOADT8(bA, gA, s + (j + 4) * 128);
        COMP8(bB, gB); LOADT8(bB, gB, s + (j + 5) * 128);
        COMP8(bC, gC); LOADT8(bC, gC, s + (j + 6) * 128);
        COMP8(bD, gD); LOADT8(bD, gD, s + (j + 7) * 128);
    }
    COMP8(bA, gA);                                  // tile 20
    COMP8(bB, gB); COMP8(bC, gC); COMP8(bD, gD);    // tiles 21..23
    LOADT8(bA, gA, s + 24 * 128);
    COMP8(bA, gA);                                  // tile 24 (clamped for s>=70)

    #pragma unroll
    for (int off = 1; off < 16; off <<= 1)
        #pragma unroll
        for (int rt = 0; rt < 4; ++rt)
            #pragma unroll
            for (int r = 0; r < 4; ++r)
                sums[rt][r] += __shfl_xor(sums[rt][r], off, 64);

    if (col16 == 0) {
        #pragma unroll
        for (int rt = 0; rt < 4; ++rt)
            #pragma unroll
            for (int r = 0; r < 4; ++r) {
                const int row = rowbase + rt * 16 + quad * 4 + r;
                part_s[row * NSTREAM + s] = sums[rt][r];
            }
    }
}

// ---------------- Kernel C: finalize (fp8 ctx gather, L2-hot), one atomic/block ----------------
__global__ __launch_bounds__(256) void k_final(
    const float* __restrict__ z, const unsigned char* __restrict__ w8,
    const float* __restrict__ b_gen, const int* __restrict__ ctxw,
    const float* __restrict__ part_s, const float* __restrict__ kl,
    float* __restrict__ out)
{
    const int t = threadIdx.x;
    const int wv = t >> 6;
    const int lane = t & 63;
    __shared__ float red[4];

    float wsum = 0.f;
    #pragma unroll
    for (int rr = 0; rr < 2; ++rr) {
        const int b = blockIdx.x * 8 + wv * 2 + rr;

        int idxs[C];
        #pragma unroll
        for (int c = 0; c < C; ++c) idxs[c] = ctxw[b * C + c];
        unsigned short uw[C];
        #pragma unroll
        for (int c = 0; c < C; ++c)
            uw[c] = *(const unsigned short*)(w8 + (size_t)idxs[c] * D + lane * 2);
        float sum_bg = 0.f;
        #pragma unroll
        for (int c = 0; c < C; ++c) sum_bg += b_gen[idxs[c]];

        float sv = part_s[b * NSTREAM + lane] + part_s[b * NSTREAM + 64 + lane];
        const float z0 = z[b * D + lane * 2];
        const float z1 = z[b * D + lane * 2 + 1];

        float acc = 0.f;
        #pragma unroll
        for (int c = 0; c < C; ++c) {
            const float2v wf = __builtin_amdgcn_cvt_pk_f32_fp8((int)uw[c], false);
            acc = fmaf(z0, wf[0], acc);
            acc = fmaf(z1, wf[1], acc);
        }
        #pragma unroll
        for (int off = 32; off > 0; off >>= 1) {
            sv  += __shfl_xor(sv, off, 64);
            acc += __shfl_xor(acc, off, 64);
        }
        if (lane == 0) {
            const float lse = logf(sv);
            const float recon = acc + sum_bg - C * lse;
            wsum += kl[b] - recon;
        }
    }
    if (lane == 0) red[wv] = wsum;
    __syncthreads();
    if (t == 0) atomicAdd(out, (red[0] + red[1] + red[2] + red[3]) * (1.f / B));
}

extern "C" void kernel_launch(void* const* d_in, const int* in_sizes, int n_in,
                              void* d_out, int out_size, void* d_ws, size_t ws_size,
                              hipStream_t stream) {
    const int* x_batch = (const int*)d_in[0];
    const int* ctxw    = (const int*)d_in[1];
    const float* eps   = (const float*)d_in[2];
    const float* inf_emb = (const float*)d_in[3];
    const float* W_aff = (const float*)d_in[4];
    const float* b_aff = (const float*)d_in[5];
    const float* W_mu  = (const float*)d_in[6];
    const float* b_mu  = (const float*)d_in[7];
    const float* W_sig = (const float*)d_in[8];
    const float* b_sig = (const float*)d_in[9];
    const float* gen_sig = (const float*)d_in[10];
    const float* W_gen = (const float*)d_in[11];
    const float* b_gen = (const float*)d_in[12];
    float* out = (float*)d_out;

    char* ws = (char*)d_ws;
    float* z      = (float*)ws;   ws += (size_t)B * D * 4;
    float* part_s = (float*)ws;   ws += (size_t)B * NSTREAM * 4;
    float* kl     = (float*)ws;   ws += (size_t)B * 4;
    float* bg2    = (float*)ws;   ws += (size_t)NVPAD * 4;
    unsigned char* z8 = (unsigned char*)ws;  ws += (size_t)B * D;
    unsigned char* w8 = (unsigned char*)ws;  ws += (size_t)NVPAD * D;
    short* waff_bf = (short*)ws;  ws += (size_t)128 * 256 * 2;
    short* wmu_bf  = (short*)ws;  ws += (size_t)128 * 128 * 2;
    short* wsig_bf = (short*)ws;  ws += (size_t)128 * 128 * 2;

    const int pre_items = 16384 + NVPAD / 4;
    hipLaunchKernelGGL(k_pre, dim3((pre_items + 255) / 256), dim3(256), 0, stream,
                       W_aff, W_mu, W_sig, b_gen,
                       waff_bf, wmu_bf, wsig_bf, bg2, out);
    hipLaunchKernelGGL(k_main, dim3(128 + CONVB), dim3(640), 0, stream,
                       x_batch, ctxw, eps, inf_emb, waff_bf, b_aff, wmu_bf, b_mu,
                       wsig_bf, b_sig, gen_sig, W_gen, w8, z, z8, kl);
    hipLaunchKernelGGL(k_lse_mfma, dim3(8 * NSTREAM), dim3(256), 0, stream,
                       z8, w8, bg2, part_s);
    hipLaunchKernelGGL(k_final, dim3(B / 8), dim3(256), 0, stream,
                       z, w8, b_gen, ctxw, part_s, kl, out);
}